// Round 5
// baseline (630.471 us; speedup 1.0000x reference)
//
#include <hip/hip_runtime.h>
#include <hip/hip_fp16.h>

#define HH 1080
#define WW 1920
#define NB 8
#define HWP (HH*WW)                 // 2,073,600
#define NPXs ((size_t)NB*HWP)       // 16,588,800
#define NC4 (WW/4)                  // 480 groups of 4 halves

// LDS pad for K1: +1 word every 32
#define PADI(e) ((e) + ((e) >> 5))

__device__ __forceinline__ int reflH(int y){ int r = y < 0 ? -y : y; return r >= HH ? 2*HH-2-r : r; }

__device__ __forceinline__ unsigned pkmin(unsigned a, unsigned b){
    unsigned r; asm("v_pk_min_f16 %0, %1, %2" : "=v"(r) : "v"(a), "v"(b)); return r;
}
#define INF2 0x7C007C00u

// ---------------------------------------------------------------- K1: dark channel + horizontal erosion
__global__ __launch_bounds__(256) void k_dark_eh(const float* __restrict__ I,
                                                 __half* __restrict__ dark, __half* __restrict__ eh){
    __shared__ float ds[2048];
    int bid = blockIdx.x;
    int y = bid % HH;
    int b = bid / HH;
    const float* row0 = I + (size_t)b*3*HWP + (size_t)y*WW;
    size_t rb = (size_t)b*HWP + (size_t)y*WW;
    int tid = threadIdx.x;
    if (tid < 240){
        int x0 = tid*8;
        float4 c00 = *(const float4*)(row0 + x0);
        float4 c01 = *(const float4*)(row0 + x0 + 4);
        float4 c10 = *(const float4*)(row0 + HWP + x0);
        float4 c11 = *(const float4*)(row0 + HWP + x0 + 4);
        float4 c20 = *(const float4*)(row0 + 2*HWP + x0);
        float4 c21 = *(const float4*)(row0 + 2*HWP + x0 + 4);
        float m[8];
        m[0]=fminf(fminf(c00.x,c10.x),c20.x); m[1]=fminf(fminf(c00.y,c10.y),c20.y);
        m[2]=fminf(fminf(c00.z,c10.z),c20.z); m[3]=fminf(fminf(c00.w,c10.w),c20.w);
        m[4]=fminf(fminf(c01.x,c11.x),c21.x); m[5]=fminf(fminf(c01.y,c11.y),c21.y);
        m[6]=fminf(fminf(c01.z,c11.z),c21.z); m[7]=fminf(fminf(c01.w,c11.w),c21.w);
        __half2 hd[4];
        #pragma unroll
        for (int l=0;l<4;++l) hd[l] = __floats2half2_rn(m[2*l], m[2*l+1]);
        *(uint4*)(dark + rb + x0) = *(uint4*)hd;
        #pragma unroll
        for (int i=0;i<8;++i) ds[PADI(x0+7+i)] = m[i];
    } else if (tid == 240){
        for (int i=0;i<7;++i) ds[PADI(i)] = 1e30f;
    } else if (tid == 241){
        for (int i=0;i<7;++i) ds[PADI(1927+i)] = 1e30f;
    }
    __syncthreads();
    if (tid >= 240) return;
    int x0 = tid*8;
    float s[22];
    #pragma unroll
    for (int i=0;i<22;++i) s[i] = ds[PADI(x0+i)];
    float t1[21], t2[19], t4[15];
    #pragma unroll
    for (int i=0;i<21;++i) t1[i] = fminf(s[i], s[i+1]);
    #pragma unroll
    for (int i=0;i<19;++i) t2[i] = fminf(t1[i], t1[i+2]);
    #pragma unroll
    for (int i=0;i<15;++i) t4[i] = fminf(t2[i], t2[i+4]);
    __half2 ho[4];
    #pragma unroll
    for (int l=0;l<4;++l){
        float o0 = fminf(t4[2*l],   t4[2*l+7]);
        float o1 = fminf(t4[2*l+1], t4[2*l+8]);
        ho[l] = __floats2half2_rn(o0, o1);
    }
    *(uint4*)(eh + rb + x0) = *(uint4*)ho;
}

// ---------------------------------------------------------------- K2: vertical erosion (window 15) via suffix/prefix
__global__ __launch_bounds__(256) void k_erosv(const __half* __restrict__ eh, __half* __restrict__ dim){
    int t = blockIdx.x*256 + threadIdx.x;          // 480*8*72 threads, 1080 blocks
    int c4 = t % NC4;
    int r  = t / NC4;
    int b  = r & 7;
    int y0 = (r >> 3) * 15;
    const __half* sp = eh  + (size_t)b*HWP + (size_t)c4*4;
    __half*       dp = dim + (size_t)b*HWP + (size_t)c4*4;
    uint2 s[15];
    #pragma unroll
    for (int j=0;j<15;++j){
        int y = y0 - 7 + j;
        if ((unsigned)y < HH) s[j] = *(const uint2*)(sp + (size_t)y*WW);
        else { s[j].x = INF2; s[j].y = INF2; }
    }
    #pragma unroll
    for (int j=13;j>=0;--j){
        s[j].x = pkmin(s[j].x, s[j+1].x); s[j].y = pkmin(s[j].y, s[j+1].y);
    }
    *(uint2*)(dp + (size_t)y0*WW) = s[0];
    uint2 P; P.x = INF2; P.y = INF2;
    #pragma unroll
    for (int j=1;j<15;++j){
        int y = y0 + 7 + j;
        uint2 nv;
        if ((unsigned)y < HH) nv = *(const uint2*)(sp + (size_t)y*WW);
        else { nv.x = INF2; nv.y = INF2; }
        P.x = pkmin(P.x, nv.x); P.y = pkmin(P.y, nv.y);
        uint2 o;
        o.x = pkmin(s[j].x, P.x); o.y = pkmin(s[j].y, P.y);
        *(uint2*)(dp + (size_t)(y0+j)*WW) = o;
    }
}

// ---------------------------------------------------------------- K3: fused V-blur + H-blur + a,b + H-blur(a,b), wave-scan version
// Scan cells s=0..1984 (cell = V-running-SUM of plane at column col(s)),
//   col(s) = 32-s (s<32) | s-32 (s<=1951) | 3870-s (s<=1981); cells {0,1,2}
//   and s>=1982 are zero. Window: out[x] = P[x+62]-P[x+2], P = incl prefix.
// Wave w owns cells [448w, 448w+512), 8/lane; outputs x in [448w, 448w+448).
// Prefix assembled per-wave in registers via shfl (zero barriers, zero LDS).
// Second blur (a,b) needs cross-wave halo -> one LDS row pair, 2 barriers/row.
#define VT2 15
__global__ __launch_bounds__(320) void k_vh2(const __half* __restrict__ dimp, const __half* __restrict__ darkp,
                                             __half* __restrict__ aH, __half* __restrict__ bH){
    __shared__ float abl[2][2160];        // PAD8 over 1920 cols: +1 float per 8

    int bid = blockIdx.x;                 // 8 * (1080/VT2) = 576 blocks
    int yt = bid % (HH/VT2);
    int b  = bid / (HH/VT2);
    int y0 = yt * VT2;
    size_t pbase = (size_t)b*HWP;
    const __half* pd = dimp  + pbase;
    const __half* pk = darkp + pbase;
    int tid = threadIdx.x;
    int lane = tid & 63, wv = tid >> 6;
    int S0 = 448*wv + 8*lane;

    bool interior = (S0 >= 32) && (S0 <= 1944);
    bool produce  = (lane < 56) && (S0 < 1920);
    int cols[8]; bool valid[8]; bool anyv = false;
    #pragma unroll
    for (int i=0;i<8;++i){
        int s = S0 + i;
        if (s >= 3 && s <= 1981){
            cols[i] = (s < 32) ? (32 - s) : ((s <= 1951) ? (s - 32) : (3870 - s));
            valid[i] = true; anyv = true;
        } else { cols[i] = 0; valid[i] = false; }
    }

    float sI[8], sP[8], sIP[8], sII[8];
    #pragma unroll
    for (int i=0;i<8;++i){ sI[i]=0.f; sP[i]=0.f; sIP[i]=0.f; sII[i]=0.f; }

    auto rowAdd = [&](int yy){
        int yr = reflH(yy);
        const __half* pdr = pd + (size_t)yr*WW;
        const __half* pkr = pk + (size_t)yr*WW;
        if (interior){
            uint4 vd = *(const uint4*)(pdr + S0 - 32);
            uint4 vk = *(const uint4*)(pkr + S0 - 32);
            const __half2* hd = (const __half2*)&vd;
            const __half2* hk = (const __half2*)&vk;
            #pragma unroll
            for (int l2=0;l2<4;++l2){
                float2 fd = __half22float2(hd[l2]);
                float2 fk = __half22float2(hk[l2]);
                sI[2*l2]   += fd.x;  sI[2*l2+1]  += fd.y;
                sP[2*l2]   += fk.x;  sP[2*l2+1]  += fk.y;
                sIP[2*l2]  = fmaf(fd.x, fk.x, sIP[2*l2]);  sIP[2*l2+1] = fmaf(fd.y, fk.y, sIP[2*l2+1]);
                sII[2*l2]  = fmaf(fd.x, fd.x, sII[2*l2]);  sII[2*l2+1] = fmaf(fd.y, fd.y, sII[2*l2+1]);
            }
        } else if (anyv){
            #pragma unroll
            for (int i=0;i<8;++i) if (valid[i]){
                float d  = __half2float(pdr[cols[i]]);
                float k2 = __half2float(pkr[cols[i]]);
                sI[i] += d; sP[i] += k2;
                sIP[i] = fmaf(d, k2, sIP[i]); sII[i] = fmaf(d, d, sII[i]);
            }
        }
    };
    auto rowSub = [&](int yy){
        int yr = reflH(yy);
        const __half* pdr = pd + (size_t)yr*WW;
        const __half* pkr = pk + (size_t)yr*WW;
        if (interior){
            uint4 vd = *(const uint4*)(pdr + S0 - 32);
            uint4 vk = *(const uint4*)(pkr + S0 - 32);
            const __half2* hd = (const __half2*)&vd;
            const __half2* hk = (const __half2*)&vk;
            #pragma unroll
            for (int l2=0;l2<4;++l2){
                float2 fd = __half22float2(hd[l2]);
                float2 fk = __half22float2(hk[l2]);
                sI[2*l2]   -= fd.x;  sI[2*l2+1]  -= fd.y;
                sP[2*l2]   -= fk.x;  sP[2*l2+1]  -= fk.y;
                sIP[2*l2]  = fmaf(-fd.x, fk.x, sIP[2*l2]);  sIP[2*l2+1] = fmaf(-fd.y, fk.y, sIP[2*l2+1]);
                sII[2*l2]  = fmaf(-fd.x, fd.x, sII[2*l2]);  sII[2*l2+1] = fmaf(-fd.y, fd.y, sII[2*l2+1]);
            }
        } else if (anyv){
            #pragma unroll
            for (int i=0;i<8;++i) if (valid[i]){
                float d  = __half2float(pdr[cols[i]]);
                float k2 = __half2float(pkr[cols[i]]);
                sI[i] -= d; sP[i] -= k2;
                sIP[i] = fmaf(-d, k2, sIP[i]); sII[i] = fmaf(-d, d, sII[i]);
            }
        }
    };

    // wave-local scan + window diff: diff[i] = P[S0+i+62] - P[S0+i+2]
    auto scanwin = [&](const float* v, float* diff){
        float lp[8];
        lp[0] = v[0];
        #pragma unroll
        for (int i=1;i<8;++i) lp[i] = lp[i-1] + v[i];
        float sc = lp[7];
        #pragma unroll
        for (int d=1; d<64; d<<=1){
            float t = __shfl_up(sc, d);
            if (lane >= d) sc += t;
        }
        float B = sc - lp[7];
        float p[8];
        #pragma unroll
        for (int i=0;i<8;++i) p[i] = B + lp[i];
        float p0n = __shfl_down(p[0], 1), p1n = __shfl_down(p[1], 1);
        float p6a = __shfl_down(p[6], 7), p7a = __shfl_down(p[7], 7);
        float p8k0 = __shfl_down(p[0], 8), p8k1 = __shfl_down(p[1], 8);
        float p8k2 = __shfl_down(p[2], 8), p8k3 = __shfl_down(p[3], 8);
        float p8k4 = __shfl_down(p[4], 8), p8k5 = __shfl_down(p[5], 8);
        diff[0] = p6a  - p[2];
        diff[1] = p7a  - p[3];
        diff[2] = p8k0 - p[4];
        diff[3] = p8k1 - p[5];
        diff[4] = p8k2 - p[6];
        diff[5] = p8k3 - p[7];
        diff[6] = p8k4 - p0n;
        diff[7] = p8k5 - p1n;
    };

    // cold start: rows y0-29 .. y0+30
    #pragma unroll 1
    for (int k2=-29;k2<=30;++k2) rowAdd(y0+k2);

    const float inv  = 1.0f/60.0f;
    const float inv2 = 1.0f/3600.0f;
    int padbase_w = (S0 - 32) >> 3;        // interior LDS-read pad offset
    int padbase_o = S0 >> 3;               // output LDS-write pad offset

    #pragma unroll 1
    for (int y=y0; y<y0+VT2; ++y){
        if (y > y0){ rowAdd(y+30); rowSub(y-30); }

        float dI[8], dP[8], dIP[8], dII[8];
        scanwin(sI, dI); scanwin(sP, dP); scanwin(sIP, dIP); scanwin(sII, dII);

        float Aa[8], Bb[8];
        #pragma unroll
        for (int i=0;i<8;++i){
            float mI = dI[i]*inv2, mP = dP[i]*inv2, mIp = dIP[i]*inv2, mII = dII[i]*inv2;
            float cov = mIp - mI*mP;
            float var = mII - mI*mI;
            float a = cov / (var + 1e-4f);
            Aa[i] = a; Bb[i] = mP - a*mI;
        }

        __syncthreads();
        if (produce){
            #pragma unroll
            for (int i=0;i<8;++i){
                abl[0][S0 + i + padbase_o] = Aa[i];
                abl[1][S0 + i + padbase_o] = Bb[i];
            }
        }
        __syncthreads();

        float av[8], bv[8];
        if (interior){
            #pragma unroll
            for (int i=0;i<8;++i){
                int pi = (S0 - 32) + i + padbase_w;
                av[i] = abl[0][pi]; bv[i] = abl[1][pi];
            }
        } else {
            #pragma unroll
            for (int i=0;i<8;++i){
                if (valid[i]){ int pi = cols[i] + (cols[i] >> 3); av[i] = abl[0][pi]; bv[i] = abl[1][pi]; }
                else { av[i] = 0.f; bv[i] = 0.f; }
            }
        }
        float dA[8], dB[8];
        scanwin(av, dA); scanwin(bv, dB);

        if (produce){
            __half2 ha[4], hb[4];
            #pragma unroll
            for (int l2=0;l2<4;++l2){
                ha[l2] = __floats2half2_rn(dA[2*l2]*inv, dA[2*l2+1]*inv);
                hb[l2] = __floats2half2_rn(dB[2*l2]*inv, dB[2*l2+1]*inv);
            }
            size_t ro = pbase + (size_t)y*WW + S0;
            *(uint4*)(aH + ro) = *(uint4*)ha;
            *(uint4*)(bH + ro) = *(uint4*)hb;
        }
    }
}

// ---------------------------------------------------------------- K4: vertical box-mean of aH,bH + q
#define BT 18
__global__ __launch_bounds__(256) void k_final(const __half* __restrict__ aHp, const __half* __restrict__ bHp,
                                               const __half* __restrict__ dimp, float* __restrict__ q){
    int t = blockIdx.x*256 + threadIdx.x;          // 480*8*60 threads, 900 blocks
    int c4 = t % NC4;
    int r  = t / NC4;
    int b  = r & 7;
    int y0 = (r >> 3) * BT;
    size_t base = (size_t)b*HWP + (size_t)c4*4;
    const __half* pa = aHp + base;
    const __half* pb = bHp + base;
    const __half* pd = dimp + base;
    float* pq = q + base;
    float sa[4], sb[4];
    #pragma unroll
    for (int i=0;i<4;++i){ sa[i]=0.f; sb[i]=0.f; }
    auto accA = [&](int yy){
        int yr = reflH(yy);
        uint2 va = *(const uint2*)(pa + (size_t)yr*WW);
        uint2 vb = *(const uint2*)(pb + (size_t)yr*WW);
        const __half2* hA = (const __half2*)&va;
        const __half2* hB = (const __half2*)&vb;
        #pragma unroll
        for (int l=0;l<2;++l){
            float2 fa = __half22float2(hA[l]);
            float2 fb = __half22float2(hB[l]);
            sa[2*l]+=fa.x; sa[2*l+1]+=fa.y;
            sb[2*l]+=fb.x; sb[2*l+1]+=fb.y;
        }
    };
    auto accS = [&](int yy){
        int yr = reflH(yy);
        uint2 va = *(const uint2*)(pa + (size_t)yr*WW);
        uint2 vb = *(const uint2*)(pb + (size_t)yr*WW);
        const __half2* hA = (const __half2*)&va;
        const __half2* hB = (const __half2*)&vb;
        #pragma unroll
        for (int l=0;l<2;++l){
            float2 fa = __half22float2(hA[l]);
            float2 fb = __half22float2(hB[l]);
            sa[2*l]-=fa.x; sa[2*l+1]-=fa.y;
            sb[2*l]-=fb.x; sb[2*l+1]-=fb.y;
        }
    };
    const float inv = 1.0f/60.0f;
    for (int k=-29;k<=30;++k) accA(y0+k);
    auto emit = [&](int y){
        uint2 vd = *(const uint2*)(pd + (size_t)y*WW);
        const __half2* hd = (const __half2*)&vd;
        float2 f0 = __half22float2(hd[0]);
        float2 f1 = __half22float2(hd[1]);
        float4 o;
        o.x = (sa[0]*inv)*f0.x + sb[0]*inv;
        o.y = (sa[1]*inv)*f0.y + sb[1]*inv;
        o.z = (sa[2]*inv)*f1.x + sb[2]*inv;
        o.w = (sa[3]*inv)*f1.y + sb[3]*inv;
        *(float4*)(pq + (size_t)y*WW) = o;
    };
    emit(y0);
    for (int y=y0+1; y<y0+BT; ++y){
        accA(y+30);
        accS(y-30);
        emit(y);
    }
}

// ---------------------------------------------------------------- launch
extern "C" void kernel_launch(void* const* d_in, const int* in_sizes, int n_in,
                              void* d_out, int out_size, void* d_ws, size_t ws_size,
                              hipStream_t stream){
    const float* I = (const float*)d_in[0];
    float* qout = (float*)d_out;
    __half* ws = (__half*)d_ws;

    __half* p_dark = ws;
    __half* p_eh   = ws + NPXs;
    __half* p_dim  = ws + 2*NPXs;
    __half* p_aH   = ws + 3*NPXs;
    __half* p_bH   = ws + 4*NPXs;

    k_dark_eh<<<NB*HH,          256, 0, stream>>>(I, p_dark, p_eh);
    k_erosv  <<<1080,           256, 0, stream>>>(p_eh, p_dim);
    k_vh2    <<<NB*(HH/VT2),    320, 0, stream>>>(p_dim, p_dark, p_aH, p_bH);
    k_final  <<<900,            256, 0, stream>>>(p_aH, p_bH, p_dim, qout);
}

// Round 6
// 261.736 us; speedup vs baseline: 2.4088x; 2.4088x over previous
//
#include <hip/hip_runtime.h>
#include <hip/hip_fp16.h>

#define HH 1080
#define WW 1920
#define NB 8
#define HWP (HH*WW)                 // 2,073,600
#define NPXs ((size_t)NB*HWP)       // 16,588,800
#define NC4 (WW/4)                  // 480 groups of 4 halves

// LDS pad for K1: +1 word every 32
#define PADI(e) ((e) + ((e) >> 5))

__device__ __forceinline__ int reflH(int y){ int r = y < 0 ? -y : y; return r >= HH ? 2*HH-2-r : r; }

// XCD-chunked block swizzle: grid = 8*q blocks, physical p -> logical (p&7)*q + p/8
// (hardware round-robins dispatch index over 8 XCDs -> each XCD gets a contiguous
//  logical chunk; y-adjacent blocks become XCD-local for L2 halo reuse). Bijective
// since grid % 8 == 0. Worst case (mapping assumption wrong): still a bijection.
__device__ __forceinline__ int xcd_swz(int p, int q){ return (p & 7)*q + (p >> 3); }

__device__ __forceinline__ unsigned pkmin(unsigned a, unsigned b){
    unsigned r; asm("v_pk_min_f16 %0, %1, %2" : "=v"(r) : "v"(a), "v"(b)); return r;
}
#define INF2 0x7C007C00u

// ---------------------------------------------------------------- K1: dark channel + horizontal erosion
__global__ __launch_bounds__(256) void k_dark_eh(const float* __restrict__ I,
                                                 __half* __restrict__ dark, __half* __restrict__ eh){
    __shared__ float ds[2048];
    int bid = blockIdx.x;
    int y = bid % HH;
    int b = bid / HH;
    const float* row0 = I + (size_t)b*3*HWP + (size_t)y*WW;
    size_t rb = (size_t)b*HWP + (size_t)y*WW;
    int tid = threadIdx.x;
    if (tid < 240){
        int x0 = tid*8;
        float4 c00 = *(const float4*)(row0 + x0);
        float4 c01 = *(const float4*)(row0 + x0 + 4);
        float4 c10 = *(const float4*)(row0 + HWP + x0);
        float4 c11 = *(const float4*)(row0 + HWP + x0 + 4);
        float4 c20 = *(const float4*)(row0 + 2*HWP + x0);
        float4 c21 = *(const float4*)(row0 + 2*HWP + x0 + 4);
        float m[8];
        m[0]=fminf(fminf(c00.x,c10.x),c20.x); m[1]=fminf(fminf(c00.y,c10.y),c20.y);
        m[2]=fminf(fminf(c00.z,c10.z),c20.z); m[3]=fminf(fminf(c00.w,c10.w),c20.w);
        m[4]=fminf(fminf(c01.x,c11.x),c21.x); m[5]=fminf(fminf(c01.y,c11.y),c21.y);
        m[6]=fminf(fminf(c01.z,c11.z),c21.z); m[7]=fminf(fminf(c01.w,c11.w),c21.w);
        __half2 hd[4];
        #pragma unroll
        for (int l=0;l<4;++l) hd[l] = __floats2half2_rn(m[2*l], m[2*l+1]);
        *(uint4*)(dark + rb + x0) = *(uint4*)hd;
        #pragma unroll
        for (int i=0;i<8;++i) ds[PADI(x0+7+i)] = m[i];
    } else if (tid == 240){
        for (int i=0;i<7;++i) ds[PADI(i)] = 1e30f;
    } else if (tid == 241){
        for (int i=0;i<7;++i) ds[PADI(1927+i)] = 1e30f;
    }
    __syncthreads();
    if (tid >= 240) return;
    int x0 = tid*8;
    float s[22];
    #pragma unroll
    for (int i=0;i<22;++i) s[i] = ds[PADI(x0+i)];
    float t1[21], t2[19], t4[15];
    #pragma unroll
    for (int i=0;i<21;++i) t1[i] = fminf(s[i], s[i+1]);
    #pragma unroll
    for (int i=0;i<19;++i) t2[i] = fminf(t1[i], t1[i+2]);
    #pragma unroll
    for (int i=0;i<15;++i) t4[i] = fminf(t2[i], t2[i+4]);
    __half2 ho[4];
    #pragma unroll
    for (int l=0;l<4;++l){
        float o0 = fminf(t4[2*l],   t4[2*l+7]);
        float o1 = fminf(t4[2*l+1], t4[2*l+8]);
        ho[l] = __floats2half2_rn(o0, o1);
    }
    *(uint4*)(eh + rb + x0) = *(uint4*)ho;
}

// ---------------------------------------------------------------- K2: vertical erosion (window 15) via suffix/prefix
__global__ __launch_bounds__(256) void k_erosv(const __half* __restrict__ eh, __half* __restrict__ dim){
    int t = xcd_swz(blockIdx.x, 135)*256 + threadIdx.x;   // 1080 blocks
    int c4 = t % NC4;
    int r  = t / NC4;
    int b  = r & 7;
    int y0 = (r >> 3) * 15;
    const __half* sp = eh  + (size_t)b*HWP + (size_t)c4*4;
    __half*       dp = dim + (size_t)b*HWP + (size_t)c4*4;
    uint2 s[15];
    #pragma unroll
    for (int j=0;j<15;++j){
        int y = y0 - 7 + j;
        if ((unsigned)y < HH) s[j] = *(const uint2*)(sp + (size_t)y*WW);
        else { s[j].x = INF2; s[j].y = INF2; }
    }
    #pragma unroll
    for (int j=13;j>=0;--j){
        s[j].x = pkmin(s[j].x, s[j+1].x); s[j].y = pkmin(s[j].y, s[j+1].y);
    }
    *(uint2*)(dp + (size_t)y0*WW) = s[0];
    uint2 P; P.x = INF2; P.y = INF2;
    #pragma unroll
    for (int j=1;j<15;++j){
        int y = y0 + 7 + j;
        uint2 nv;
        if ((unsigned)y < HH) nv = *(const uint2*)(sp + (size_t)y*WW);
        else { nv.x = INF2; nv.y = INF2; }
        P.x = pkmin(P.x, nv.x); P.y = pkmin(P.y, nv.y);
        uint2 o;
        o.x = pkmin(s[j].x, P.x); o.y = pkmin(s[j].y, P.y);
        *(uint2*)(dp + (size_t)(y0+j)*WW) = o;
    }
}

// ---------------------------------------------------------------- K3: vertical box-mean of 4 moments
#define BT 27
__global__ __launch_bounds__(256) void k_blurv4(const __half* __restrict__ dimp, const __half* __restrict__ darkp,
                                                __half* __restrict__ m0, __half* __restrict__ m1,
                                                __half* __restrict__ m2, __half* __restrict__ m3){
    int t = xcd_swz(blockIdx.x, 75)*256 + threadIdx.x;    // 480*8*40 threads, 600 blocks
    int c4 = t % NC4;
    int r  = t / NC4;
    int b  = r & 7;
    int y0 = (r >> 3) * BT;
    size_t base = (size_t)b*HWP + (size_t)c4*4;
    const __half* pd = dimp + base;
    const __half* pk = darkp + base;
    float sI[4], sP[4], sIP[4], sII[4];
    #pragma unroll
    for (int i=0;i<4;++i){ sI[i]=0.f; sP[i]=0.f; sIP[i]=0.f; sII[i]=0.f; }
    auto accA = [&](int yy){
        int yr = reflH(yy);
        uint2 vd = *(const uint2*)(pd + (size_t)yr*WW);
        uint2 vk = *(const uint2*)(pk + (size_t)yr*WW);
        const __half2* hd = (const __half2*)&vd;
        const __half2* hk = (const __half2*)&vk;
        #pragma unroll
        for (int l=0;l<2;++l){
            float2 fd = __half22float2(hd[l]);
            float2 fk = __half22float2(hk[l]);
            sI[2*l]+=fd.x; sI[2*l+1]+=fd.y;
            sP[2*l]+=fk.x; sP[2*l+1]+=fk.y;
            sIP[2*l]+=fd.x*fk.x; sIP[2*l+1]+=fd.y*fk.y;
            sII[2*l]+=fd.x*fd.x; sII[2*l+1]+=fd.y*fd.y;
        }
    };
    auto accS = [&](int yy){
        int yr = reflH(yy);
        uint2 vd = *(const uint2*)(pd + (size_t)yr*WW);
        uint2 vk = *(const uint2*)(pk + (size_t)yr*WW);
        const __half2* hd = (const __half2*)&vd;
        const __half2* hk = (const __half2*)&vk;
        #pragma unroll
        for (int l=0;l<2;++l){
            float2 fd = __half22float2(hd[l]);
            float2 fk = __half22float2(hk[l]);
            sI[2*l]-=fd.x; sI[2*l+1]-=fd.y;
            sP[2*l]-=fk.x; sP[2*l+1]-=fk.y;
            sIP[2*l]-=fd.x*fk.x; sIP[2*l+1]-=fd.y*fk.y;
            sII[2*l]-=fd.x*fd.x; sII[2*l+1]-=fd.y*fd.y;
        }
    };
    const float inv = 1.0f/60.0f;
    for (int k=-29;k<=30;++k) accA(y0+k);
    auto emit = [&](int y){
        size_t off = base + (size_t)y*WW;
        __half2 h[2];
        h[0]=__floats2half2_rn(sI[0]*inv,sI[1]*inv);  h[1]=__floats2half2_rn(sI[2]*inv,sI[3]*inv);
        *(uint2*)(m0+off) = *(uint2*)h;
        h[0]=__floats2half2_rn(sP[0]*inv,sP[1]*inv);  h[1]=__floats2half2_rn(sP[2]*inv,sP[3]*inv);
        *(uint2*)(m1+off) = *(uint2*)h;
        h[0]=__floats2half2_rn(sIP[0]*inv,sIP[1]*inv); h[1]=__floats2half2_rn(sIP[2]*inv,sIP[3]*inv);
        *(uint2*)(m2+off) = *(uint2*)h;
        h[0]=__floats2half2_rn(sII[0]*inv,sII[1]*inv); h[1]=__floats2half2_rn(sII[2]*inv,sII[3]*inv);
        *(uint2*)(m3+off) = *(uint2*)h;
    };
    emit(y0);
    for (int y=y0+1; y<y0+BT; ++y){
        accA(y+30);
        accS(y-30);
        emit(y);
    }
}

// ---------------------------------------------------------------- K4: H-blur(moments) + a,b + H-blur(a,b) via prefix scans
// Padded seq: xp[j] = m[reflW(j-29)], j=0..1978. out[x] = sum_{j=x..x+59} xp[j].
// Scan index s = j+3 (zeros for s<3, s>1981). Thread u owns s=8u..8u+7.
// PiS[z] = Pi[z+2] (inclusive prefix), stored de-interleaved: chunk c=z>>2,
//   c even -> PA[c>>1], c odd -> PB[c>>1]. out[x] = PiS[x+60]-PiS[x].
// Second blur over x-grid with reflect corrections, PrS[z] holds Pr[z-30].
__global__ __launch_bounds__(256) void k_hab(const __half* __restrict__ m0, const __half* __restrict__ m1,
                                             const __half* __restrict__ m2, const __half* __restrict__ m3,
                                             __half* __restrict__ aH, __half* __restrict__ bH){
    __shared__ float4 PA[4][256];
    __shared__ float4 PB[4][256];
    __shared__ float4 QA[2][264];
    __shared__ float4 QB[2][264];
    __shared__ float wt[4][4];
    __shared__ float wt2[2][4];

    int bid = blockIdx.x;
    int y = bid % HH;
    int b = bid / HH;
    size_t rb = (size_t)b*HWP + (size_t)y*WW;
    int tid = threadIdx.x;
    int lane = tid & 63;
    int wv = tid >> 6;

    const __half* mp0 = m0 + rb; const __half* mp1 = m1 + rb;
    const __half* mp2 = m2 + rb; const __half* mp3 = m3 + rb;

    // ---- scan-input loads
    float xv[4][8];
    int u = tid;
    if (u >= 4 && u <= 243){
        int x0 = 8*(u-4);
        const __half* mp[4] = {mp0, mp1, mp2, mp3};
        #pragma unroll
        for (int p=0;p<4;++p){
            uint4 hv = *(const uint4*)(mp[p] + x0);
            const __half2* h2 = (const __half2*)&hv;
            #pragma unroll
            for (int l=0;l<4;++l){
                float2 f = __half22float2(h2[l]);
                xv[p][2*l] = f.x; xv[p][2*l+1] = f.y;
            }
        }
    } else {
        #pragma unroll
        for (int i=0;i<8;++i){
            int s = 8*u + i;
            if (s >= 3 && s <= 1981){
                int j = s - 3;
                int x = j - 29;
                if (x < 0) x = -x;
                else if (x > 1919) x = 3838 - x;
                xv[0][i] = __half2float(mp0[x]);
                xv[1][i] = __half2float(mp1[x]);
                xv[2][i] = __half2float(mp2[x]);
                xv[3][i] = __half2float(mp3[x]);
            } else {
                xv[0][i]=0.f; xv[1][i]=0.f; xv[2][i]=0.f; xv[3][i]=0.f;
            }
        }
    }

    // ---- local prefix + wave scan
    float ebase[4];
    #pragma unroll
    for (int p=0;p<4;++p){
        #pragma unroll
        for (int i=1;i<8;++i) xv[p][i] += xv[p][i-1];
        float v = xv[p][7];
        #pragma unroll
        for (int d=1; d<64; d<<=1){
            float tmp = __shfl_up(v, d);
            if (lane >= d) v += tmp;
        }
        ebase[p] = v - xv[p][7];
        if (lane == 63) wt[p][wv] = v;
    }
    __syncthreads();
    #pragma unroll
    for (int p=0;p<4;++p){
        float bb = ebase[p];
        if (wv > 0) bb += wt[p][0];
        if (wv > 1) bb += wt[p][1];
        if (wv > 2) bb += wt[p][2];
        #pragma unroll
        for (int i=0;i<8;++i) xv[p][i] += bb;   // xv[p][i] = Pi[8u+i]
        if (u > 0) *((float2*)&PB[p][u-1] + 1) = make_float2(xv[p][0], xv[p][1]);
        PA[p][u] = make_float4(xv[p][2], xv[p][3], xv[p][4], xv[p][5]);
        *((float2*)&PB[p][u]) = make_float2(xv[p][6], xv[p][7]);
    }
    __syncthreads();

    // ---- phase 3a: window means + a,b
    float Aa[8], Bb[8];
    int t = tid;
    if (t < 240){
        const float inv = 1.0f/60.0f;
        float mm[4][8];
        #pragma unroll
        for (int p=0;p<4;++p){
            float4 loa = PA[p][t];
            float4 lob = PB[p][t];
            float4 hib = PB[p][t+7];
            float4 hia = PA[p][t+8];
            mm[p][0]=(hib.x-loa.x)*inv; mm[p][1]=(hib.y-loa.y)*inv;
            mm[p][2]=(hib.z-loa.z)*inv; mm[p][3]=(hib.w-loa.w)*inv;
            mm[p][4]=(hia.x-lob.x)*inv; mm[p][5]=(hia.y-lob.y)*inv;
            mm[p][6]=(hia.z-lob.z)*inv; mm[p][7]=(hia.w-lob.w)*inv;
        }
        #pragma unroll
        for (int i=0;i<8;++i){
            float mI=mm[0][i], mP=mm[1][i], mIp=mm[2][i], mII=mm[3][i];
            float cov = mIp - mI*mP;
            float var = mII - mI*mI;
            float a = cov / (var + 1e-4f);
            Aa[i] = a;
            Bb[i] = mP - a*mI;
        }
    } else {
        #pragma unroll
        for (int i=0;i<8;++i){ Aa[i]=0.f; Bb[i]=0.f; }
    }

    // ---- scan2 over a and b (x-grid, 1920 values in threads 0..239)
    float eA, eB;
    {
        #pragma unroll
        for (int i=1;i<8;++i) Aa[i] += Aa[i-1];
        float v = Aa[7];
        #pragma unroll
        for (int d=1; d<64; d<<=1){
            float tmp = __shfl_up(v, d);
            if (lane >= d) v += tmp;
        }
        eA = v - Aa[7];
        if (lane==63) wt2[0][wv] = v;
    }
    {
        #pragma unroll
        for (int i=1;i<8;++i) Bb[i] += Bb[i-1];
        float v = Bb[7];
        #pragma unroll
        for (int d=1; d<64; d<<=1){
            float tmp = __shfl_up(v, d);
            if (lane >= d) v += tmp;
        }
        eB = v - Bb[7];
        if (lane==63) wt2[1][wv] = v;
    }
    __syncthreads();
    {
        float bb = eA;
        if (wv>0) bb += wt2[0][0];
        if (wv>1) bb += wt2[0][1];
        if (wv>2) bb += wt2[0][2];
        #pragma unroll
        for (int i=0;i<8;++i) Aa[i] += bb;      // Aa[i] = Pr_a[8t+i]
        bb = eB;
        if (wv>0) bb += wt2[1][0];
        if (wv>1) bb += wt2[1][1];
        if (wv>2) bb += wt2[1][2];
        #pragma unroll
        for (int i=0;i<8;++i) Bb[i] += bb;
    }
    // PrS writes: cells z=8t+30..8t+37 hold Pr[8t..8t+7]
    *((float2*)&QB[0][t+3] + 1) = make_float2(Aa[0], Aa[1]);
    QA[0][t+4] = make_float4(Aa[2], Aa[3], Aa[4], Aa[5]);
    *((float2*)&QB[0][t+4]) = make_float2(Aa[6], Aa[7]);
    *((float2*)&QB[1][t+3] + 1) = make_float2(Bb[0], Bb[1]);
    QA[1][t+4] = make_float4(Bb[2], Bb[3], Bb[4], Bb[5]);
    *((float2*)&QB[1][t+4]) = make_float2(Bb[6], Bb[7]);
    if (tid >= 248){
        int k = tid - 248;
        float4 z4 = make_float4(0.f,0.f,0.f,0.f);
        if (k < 4){ QA[0][k] = z4; QA[1][k] = z4; }
        else if (k < 7){ QB[0][k-4] = z4; QB[1][k-4] = z4; }
        else { *((float2*)&QB[0][3]) = make_float2(0.f,0.f);
               *((float2*)&QB[1][3]) = make_float2(0.f,0.f); }
    }
    __syncthreads();
    if (t >= 240) return;

    // ---- phase 3c: second blur outputs
    int x0 = 8*t;
    float4 lA0 = QA[0][t];   float4 lA1 = QB[0][t];
    float4 hA0 = QB[0][t+7]; float4 hA1 = QA[0][t+8];
    float4 lB0 = QA[1][t];   float4 lB1 = QB[1][t];
    float4 hB0 = QB[1][t+7]; float4 hB1 = QA[1][t+8];
    float sA[8], sB[8];
    sA[0]=hA0.x-lA0.x; sA[1]=hA0.y-lA0.y; sA[2]=hA0.z-lA0.z; sA[3]=hA0.w-lA0.w;
    sA[4]=hA1.x-lA1.x; sA[5]=hA1.y-lA1.y; sA[6]=hA1.z-lA1.z; sA[7]=hA1.w-lA1.w;
    sB[0]=hB0.x-lB0.x; sB[1]=hB0.y-lB0.y; sB[2]=hB0.z-lB0.z; sB[3]=hB0.w-lB0.w;
    sB[4]=hB1.x-lB1.x; sB[5]=hB1.y-lB1.y; sB[6]=hB1.z-lB1.z; sB[7]=hB1.w-lB1.w;

    auto prRead = [&](int pl, int v)->float{
        int z = v + 30;
        int c = z >> 2;
        float4 f = (c & 1) ? QB[pl][c>>1] : QA[pl][c>>1];
        int w = z & 3;
        return (w==0)?f.x:((w==1)?f.y:((w==2)?f.z:f.w));
    };
    if (x0 < 29){
        #pragma unroll
        for (int i=0;i<8;++i){
            int x = x0 + i;
            if (x < 29){
                sA[i] += prRead(0, 29-x) - prRead(0, 0);
                sB[i] += prRead(1, 29-x) - prRead(1, 0);
            }
        }
    }
    if (x0 + 7 > 1889){
        #pragma unroll
        for (int i=0;i<8;++i){
            int x = x0 + i;
            if (x > 1889){
                sA[i] += prRead(0, 1918) - prRead(0, 3807-x);
                sB[i] += prRead(1, 1918) - prRead(1, 3807-x);
            }
        }
    }
    const float inv = 1.0f/60.0f;
    __half2 ha[4], hb[4];
    #pragma unroll
    for (int l=0;l<4;++l){
        ha[l] = __floats2half2_rn(sA[2*l]*inv, sA[2*l+1]*inv);
        hb[l] = __floats2half2_rn(sB[2*l]*inv, sB[2*l+1]*inv);
    }
    *(uint4*)(aH + rb + x0) = *(uint4*)ha;
    *(uint4*)(bH + rb + x0) = *(uint4*)hb;
}

// ---------------------------------------------------------------- K5: vertical box-mean of aH,bH + q
__global__ __launch_bounds__(256) void k_final(const __half* __restrict__ aHp, const __half* __restrict__ bHp,
                                               const __half* __restrict__ dimp, float* __restrict__ q){
    int t = xcd_swz(blockIdx.x, 75)*256 + threadIdx.x;    // 480*8*40 threads, 600 blocks
    int c4 = t % NC4;
    int r  = t / NC4;
    int b  = r & 7;
    int y0 = (r >> 3) * BT;
    size_t base = (size_t)b*HWP + (size_t)c4*4;
    const __half* pa = aHp + base;
    const __half* pb = bHp + base;
    const __half* pd = dimp + base;
    float* pq = q + base;
    float sa[4], sb[4];
    #pragma unroll
    for (int i=0;i<4;++i){ sa[i]=0.f; sb[i]=0.f; }
    auto accA = [&](int yy){
        int yr = reflH(yy);
        uint2 va = *(const uint2*)(pa + (size_t)yr*WW);
        uint2 vb = *(const uint2*)(pb + (size_t)yr*WW);
        const __half2* hA = (const __half2*)&va;
        const __half2* hB = (const __half2*)&vb;
        #pragma unroll
        for (int l=0;l<2;++l){
            float2 fa = __half22float2(hA[l]);
            float2 fb = __half22float2(hB[l]);
            sa[2*l]+=fa.x; sa[2*l+1]+=fa.y;
            sb[2*l]+=fb.x; sb[2*l+1]+=fb.y;
        }
    };
    auto accS = [&](int yy){
        int yr = reflH(yy);
        uint2 va = *(const uint2*)(pa + (size_t)yr*WW);
        uint2 vb = *(const uint2*)(pb + (size_t)yr*WW);
        const __half2* hA = (const __half2*)&va;
        const __half2* hB = (const __half2*)&vb;
        #pragma unroll
        for (int l=0;l<2;++l){
            float2 fa = __half22float2(hA[l]);
            float2 fb = __half22float2(hB[l]);
            sa[2*l]-=fa.x; sa[2*l+1]-=fa.y;
            sb[2*l]-=fb.x; sb[2*l+1]-=fb.y;
        }
    };
    const float inv = 1.0f/60.0f;
    for (int k=-29;k<=30;++k) accA(y0+k);
    auto emit = [&](int y){
        uint2 vd = *(const uint2*)(pd + (size_t)y*WW);
        const __half2* hd = (const __half2*)&vd;
        float2 f0 = __half22float2(hd[0]);
        float2 f1 = __half22float2(hd[1]);
        float4 o;
        o.x = (sa[0]*inv)*f0.x + sb[0]*inv;
        o.y = (sa[1]*inv)*f0.y + sb[1]*inv;
        o.z = (sa[2]*inv)*f1.x + sb[2]*inv;
        o.w = (sa[3]*inv)*f1.y + sb[3]*inv;
        *(float4*)(pq + (size_t)y*WW) = o;
    };
    emit(y0);
    for (int y=y0+1; y<y0+BT; ++y){
        accA(y+30);
        accS(y-30);
        emit(y);
    }
}

// ---------------------------------------------------------------- launch
extern "C" void kernel_launch(void* const* d_in, const int* in_sizes, int n_in,
                              void* d_out, int out_size, void* d_ws, size_t ws_size,
                              hipStream_t stream){
    const float* I = (const float*)d_in[0];
    float* qout = (float*)d_out;
    __half* ws = (__half*)d_ws;

    __half* p_dark = ws;
    __half* p_eh   = ws + NPXs;
    __half* p_dim  = ws + 2*NPXs;
    __half* p_m0   = ws + 3*NPXs;
    __half* p_m1   = ws + 4*NPXs;
    __half* p_m2   = ws + 5*NPXs;
    __half* p_m3   = ws + 6*NPXs;
    __half* p_aH   = p_dark;   // dark dead after k_blurv4
    __half* p_bH   = p_eh;     // eh dead after k_erosv

    k_dark_eh<<<NB*HH, 256, 0, stream>>>(I, p_dark, p_eh);
    k_erosv  <<<1080,  256, 0, stream>>>(p_eh, p_dim);
    k_blurv4 <<<600,   256, 0, stream>>>(p_dim, p_dark, p_m0, p_m1, p_m2, p_m3);
    k_hab    <<<NB*HH, 256, 0, stream>>>(p_m0, p_m1, p_m2, p_m3, p_aH, p_bH);
    k_final  <<<600,   256, 0, stream>>>(p_aH, p_bH, p_dim, qout);
}

// Round 7
// 246.330 us; speedup vs baseline: 2.5595x; 1.0625x over previous
//
#include <hip/hip_runtime.h>
#include <hip/hip_fp16.h>

#define HH 1080
#define WW 1920
#define NB 8
#define HWP (HH*WW)                 // 2,073,600
#define NPXs ((size_t)NB*HWP)       // 16,588,800
#define NC4 (WW/4)                  // 480 groups of 4 halves

// LDS pad for K1: +1 word every 32
#define PADI(e) ((e) + ((e) >> 5))

__device__ __forceinline__ int reflH(int y){ int r = y < 0 ? -y : y; return r >= HH ? 2*HH-2-r : r; }

// Bijective XCD-chunked swizzle (handles nwg % 8 != 0; m204 form).
// Each XCD gets a contiguous logical chunk -> y-adjacent blocks share L2 halos.
__device__ __forceinline__ int xcd_swz(int p, int nwg){
    int q = nwg >> 3, r = nwg & 7;
    int x = p & 7, idx = p >> 3;
    int start = (x < r) ? x*(q+1) : r*(q+1) + (x - r)*q;
    return start + idx;
}

__device__ __forceinline__ unsigned pkmin(unsigned a, unsigned b){
    unsigned r; asm("v_pk_min_f16 %0, %1, %2" : "=v"(r) : "v"(a), "v"(b)); return r;
}
#define INF2 0x7C007C00u

// ---------------------------------------------------------------- K1: dark channel + horizontal erosion
__global__ __launch_bounds__(256) void k_dark_eh(const float* __restrict__ I,
                                                 __half* __restrict__ dark, __half* __restrict__ eh){
    __shared__ float ds[2048];
    int bid = blockIdx.x;
    int y = bid % HH;
    int b = bid / HH;
    const float* row0 = I + (size_t)b*3*HWP + (size_t)y*WW;
    size_t rb = (size_t)b*HWP + (size_t)y*WW;
    int tid = threadIdx.x;
    if (tid < 240){
        int x0 = tid*8;
        float4 c00 = *(const float4*)(row0 + x0);
        float4 c01 = *(const float4*)(row0 + x0 + 4);
        float4 c10 = *(const float4*)(row0 + HWP + x0);
        float4 c11 = *(const float4*)(row0 + HWP + x0 + 4);
        float4 c20 = *(const float4*)(row0 + 2*HWP + x0);
        float4 c21 = *(const float4*)(row0 + 2*HWP + x0 + 4);
        float m[8];
        m[0]=fminf(fminf(c00.x,c10.x),c20.x); m[1]=fminf(fminf(c00.y,c10.y),c20.y);
        m[2]=fminf(fminf(c00.z,c10.z),c20.z); m[3]=fminf(fminf(c00.w,c10.w),c20.w);
        m[4]=fminf(fminf(c01.x,c11.x),c21.x); m[5]=fminf(fminf(c01.y,c11.y),c21.y);
        m[6]=fminf(fminf(c01.z,c11.z),c21.z); m[7]=fminf(fminf(c01.w,c11.w),c21.w);
        __half2 hd[4];
        #pragma unroll
        for (int l=0;l<4;++l) hd[l] = __floats2half2_rn(m[2*l], m[2*l+1]);
        *(uint4*)(dark + rb + x0) = *(uint4*)hd;
        #pragma unroll
        for (int i=0;i<8;++i) ds[PADI(x0+7+i)] = m[i];
    } else if (tid == 240){
        for (int i=0;i<7;++i) ds[PADI(i)] = 1e30f;
    } else if (tid == 241){
        for (int i=0;i<7;++i) ds[PADI(1927+i)] = 1e30f;
    }
    __syncthreads();
    if (tid >= 240) return;
    int x0 = tid*8;
    float s[22];
    #pragma unroll
    for (int i=0;i<22;++i) s[i] = ds[PADI(x0+i)];
    float t1[21], t2[19], t4[15];
    #pragma unroll
    for (int i=0;i<21;++i) t1[i] = fminf(s[i], s[i+1]);
    #pragma unroll
    for (int i=0;i<19;++i) t2[i] = fminf(t1[i], t1[i+2]);
    #pragma unroll
    for (int i=0;i<15;++i) t4[i] = fminf(t2[i], t2[i+4]);
    __half2 ho[4];
    #pragma unroll
    for (int l=0;l<4;++l){
        float o0 = fminf(t4[2*l],   t4[2*l+7]);
        float o1 = fminf(t4[2*l+1], t4[2*l+8]);
        ho[l] = __floats2half2_rn(o0, o1);
    }
    *(uint4*)(eh + rb + x0) = *(uint4*)ho;
}

// ---------------------------------------------------------------- K2: vertical erosion (window 15) via suffix/prefix
__global__ __launch_bounds__(256) void k_erosv(const __half* __restrict__ eh, __half* __restrict__ dim){
    int t = xcd_swz(blockIdx.x, 1080)*256 + threadIdx.x;   // 1080 blocks
    int c4 = t % NC4;
    int r  = t / NC4;
    int b  = r & 7;
    int y0 = (r >> 3) * 15;
    const __half* sp = eh  + (size_t)b*HWP + (size_t)c4*4;
    __half*       dp = dim + (size_t)b*HWP + (size_t)c4*4;
    uint2 s[15];
    #pragma unroll
    for (int j=0;j<15;++j){
        int y = y0 - 7 + j;
        if ((unsigned)y < HH) s[j] = *(const uint2*)(sp + (size_t)y*WW);
        else { s[j].x = INF2; s[j].y = INF2; }
    }
    #pragma unroll
    for (int j=13;j>=0;--j){
        s[j].x = pkmin(s[j].x, s[j+1].x); s[j].y = pkmin(s[j].y, s[j+1].y);
    }
    *(uint2*)(dp + (size_t)y0*WW) = s[0];
    uint2 P; P.x = INF2; P.y = INF2;
    #pragma unroll
    for (int j=1;j<15;++j){
        int y = y0 + 7 + j;
        uint2 nv;
        if ((unsigned)y < HH) nv = *(const uint2*)(sp + (size_t)y*WW);
        else { nv.x = INF2; nv.y = INF2; }
        P.x = pkmin(P.x, nv.x); P.y = pkmin(P.y, nv.y);
        uint2 o;
        o.x = pkmin(s[j].x, P.x); o.y = pkmin(s[j].y, P.y);
        *(uint2*)(dp + (size_t)(y0+j)*WW) = o;
    }
}

// ---------------------------------------------------------------- K3: vertical box-mean of 4 moments -> packed plane
// Packed layout: px p -> halves [4p,4p+4) = {mI, mP, mIp, mII}
#define BT 36
__global__ __launch_bounds__(256) void k_blurv4(const __half* __restrict__ dimp, const __half* __restrict__ darkp,
                                                __half* __restrict__ mp){
    int t = xcd_swz(blockIdx.x, 450)*256 + threadIdx.x;    // 480*8*30 threads, 450 blocks
    int c4 = t % NC4;
    int r  = t / NC4;
    int b  = r & 7;
    int y0 = (r >> 3) * BT;
    size_t base = (size_t)b*HWP + (size_t)c4*4;
    const __half* pd = dimp + base;
    const __half* pk = darkp + base;
    float sI[4], sP[4], sIP[4], sII[4];
    #pragma unroll
    for (int i=0;i<4;++i){ sI[i]=0.f; sP[i]=0.f; sIP[i]=0.f; sII[i]=0.f; }
    auto accA = [&](int yy){
        int yr = reflH(yy);
        uint2 vd = *(const uint2*)(pd + (size_t)yr*WW);
        uint2 vk = *(const uint2*)(pk + (size_t)yr*WW);
        const __half2* hd = (const __half2*)&vd;
        const __half2* hk = (const __half2*)&vk;
        #pragma unroll
        for (int l=0;l<2;++l){
            float2 fd = __half22float2(hd[l]);
            float2 fk = __half22float2(hk[l]);
            sI[2*l]+=fd.x; sI[2*l+1]+=fd.y;
            sP[2*l]+=fk.x; sP[2*l+1]+=fk.y;
            sIP[2*l]+=fd.x*fk.x; sIP[2*l+1]+=fd.y*fk.y;
            sII[2*l]+=fd.x*fd.x; sII[2*l+1]+=fd.y*fd.y;
        }
    };
    auto accS = [&](int yy){
        int yr = reflH(yy);
        uint2 vd = *(const uint2*)(pd + (size_t)yr*WW);
        uint2 vk = *(const uint2*)(pk + (size_t)yr*WW);
        const __half2* hd = (const __half2*)&vd;
        const __half2* hk = (const __half2*)&vk;
        #pragma unroll
        for (int l=0;l<2;++l){
            float2 fd = __half22float2(hd[l]);
            float2 fk = __half22float2(hk[l]);
            sI[2*l]-=fd.x; sI[2*l+1]-=fd.y;
            sP[2*l]-=fk.x; sP[2*l+1]-=fk.y;
            sIP[2*l]-=fd.x*fk.x; sIP[2*l+1]-=fd.y*fk.y;
            sII[2*l]-=fd.x*fd.x; sII[2*l+1]-=fd.y*fd.y;
        }
    };
    const float inv = 1.0f/60.0f;
    for (int k=-29;k<=30;++k) accA(y0+k);
    auto emit = [&](int y){
        size_t off = (base + (size_t)y*WW) * 4;   // half units in packed plane
        __half2 h[4];
        h[0]=__floats2half2_rn(sI[0]*inv,  sP[0]*inv);
        h[1]=__floats2half2_rn(sIP[0]*inv, sII[0]*inv);
        h[2]=__floats2half2_rn(sI[1]*inv,  sP[1]*inv);
        h[3]=__floats2half2_rn(sIP[1]*inv, sII[1]*inv);
        *(uint4*)(mp+off) = *(uint4*)h;
        h[0]=__floats2half2_rn(sI[2]*inv,  sP[2]*inv);
        h[1]=__floats2half2_rn(sIP[2]*inv, sII[2]*inv);
        h[2]=__floats2half2_rn(sI[3]*inv,  sP[3]*inv);
        h[3]=__floats2half2_rn(sIP[3]*inv, sII[3]*inv);
        *(uint4*)(mp+off+8) = *(uint4*)h;
    };
    emit(y0);
    for (int y=y0+1; y<y0+BT; ++y){
        accA(y+30);
        accS(y-30);
        emit(y);
    }
}

// ---------------------------------------------------------------- K4: H-blur(moments) + a,b + H-blur(a,b) via prefix scans
// Input: packed moment plane. Output: packed ab plane (px p -> halves {a,b} at [2p,2p+2)).
__global__ __launch_bounds__(256) void k_hab(const __half* __restrict__ mp, __half* __restrict__ abp){
    __shared__ float4 PA[4][256];
    __shared__ float4 PB[4][256];
    __shared__ float4 QA[2][264];
    __shared__ float4 QB[2][264];
    __shared__ float wt[4][4];
    __shared__ float wt2[2][4];

    int bid = blockIdx.x;
    int y = bid % HH;
    int b = bid / HH;
    size_t rb = (size_t)b*HWP + (size_t)y*WW;
    int tid = threadIdx.x;
    int lane = tid & 63;
    int wv = tid >> 6;

    const __half* mrow = mp + rb*4;

    // ---- scan-input loads
    float xv[4][8];
    int u = tid;
    if (u >= 4 && u <= 243){
        int x0 = 8*(u-4);
        const __half* pbase = mrow + (size_t)4*x0;
        uint4 vv[4];
        vv[0] = *(const uint4*)(pbase);
        vv[1] = *(const uint4*)(pbase + 8);
        vv[2] = *(const uint4*)(pbase + 16);
        vv[3] = *(const uint4*)(pbase + 24);
        #pragma unroll
        for (int i=0;i<8;++i){
            const __half2* hh = (const __half2*)&vv[i>>1];
            float2 fa = __half22float2(hh[(i&1)*2]);
            float2 fb = __half22float2(hh[(i&1)*2+1]);
            xv[0][i]=fa.x; xv[1][i]=fa.y; xv[2][i]=fb.x; xv[3][i]=fb.y;
        }
    } else {
        #pragma unroll
        for (int i=0;i<8;++i){
            int s = 8*u + i;
            if (s >= 3 && s <= 1981){
                int j = s - 3;
                int x = j - 29;
                if (x < 0) x = -x;
                else if (x > 1919) x = 3838 - x;
                uint2 u2 = *(const uint2*)(mrow + (size_t)4*x);
                const __half2* hh = (const __half2*)&u2;
                float2 fa = __half22float2(hh[0]);
                float2 fb = __half22float2(hh[1]);
                xv[0][i]=fa.x; xv[1][i]=fa.y; xv[2][i]=fb.x; xv[3][i]=fb.y;
            } else {
                xv[0][i]=0.f; xv[1][i]=0.f; xv[2][i]=0.f; xv[3][i]=0.f;
            }
        }
    }

    // ---- local prefix + wave scan
    float ebase[4];
    #pragma unroll
    for (int p=0;p<4;++p){
        #pragma unroll
        for (int i=1;i<8;++i) xv[p][i] += xv[p][i-1];
        float v = xv[p][7];
        #pragma unroll
        for (int d=1; d<64; d<<=1){
            float tmp = __shfl_up(v, d);
            if (lane >= d) v += tmp;
        }
        ebase[p] = v - xv[p][7];
        if (lane == 63) wt[p][wv] = v;
    }
    __syncthreads();
    #pragma unroll
    for (int p=0;p<4;++p){
        float bb = ebase[p];
        if (wv > 0) bb += wt[p][0];
        if (wv > 1) bb += wt[p][1];
        if (wv > 2) bb += wt[p][2];
        #pragma unroll
        for (int i=0;i<8;++i) xv[p][i] += bb;   // xv[p][i] = Pi[8u+i]
        if (u > 0) *((float2*)&PB[p][u-1] + 1) = make_float2(xv[p][0], xv[p][1]);
        PA[p][u] = make_float4(xv[p][2], xv[p][3], xv[p][4], xv[p][5]);
        *((float2*)&PB[p][u]) = make_float2(xv[p][6], xv[p][7]);
    }
    __syncthreads();

    // ---- phase 3a: window means + a,b
    float Aa[8], Bb[8];
    int t = tid;
    if (t < 240){
        const float inv = 1.0f/60.0f;
        float mm[4][8];
        #pragma unroll
        for (int p=0;p<4;++p){
            float4 loa = PA[p][t];
            float4 lob = PB[p][t];
            float4 hib = PB[p][t+7];
            float4 hia = PA[p][t+8];
            mm[p][0]=(hib.x-loa.x)*inv; mm[p][1]=(hib.y-loa.y)*inv;
            mm[p][2]=(hib.z-loa.z)*inv; mm[p][3]=(hib.w-loa.w)*inv;
            mm[p][4]=(hia.x-lob.x)*inv; mm[p][5]=(hia.y-lob.y)*inv;
            mm[p][6]=(hia.z-lob.z)*inv; mm[p][7]=(hia.w-lob.w)*inv;
        }
        #pragma unroll
        for (int i=0;i<8;++i){
            float mI=mm[0][i], mP=mm[1][i], mIp=mm[2][i], mII=mm[3][i];
            float cov = mIp - mI*mP;
            float var = mII - mI*mI;
            float a = cov / (var + 1e-4f);
            Aa[i] = a;
            Bb[i] = mP - a*mI;
        }
    } else {
        #pragma unroll
        for (int i=0;i<8;++i){ Aa[i]=0.f; Bb[i]=0.f; }
    }

    // ---- scan2 over a and b (x-grid, 1920 values in threads 0..239)
    float eA, eB;
    {
        #pragma unroll
        for (int i=1;i<8;++i) Aa[i] += Aa[i-1];
        float v = Aa[7];
        #pragma unroll
        for (int d=1; d<64; d<<=1){
            float tmp = __shfl_up(v, d);
            if (lane >= d) v += tmp;
        }
        eA = v - Aa[7];
        if (lane==63) wt2[0][wv] = v;
    }
    {
        #pragma unroll
        for (int i=1;i<8;++i) Bb[i] += Bb[i-1];
        float v = Bb[7];
        #pragma unroll
        for (int d=1; d<64; d<<=1){
            float tmp = __shfl_up(v, d);
            if (lane >= d) v += tmp;
        }
        eB = v - Bb[7];
        if (lane==63) wt2[1][wv] = v;
    }
    __syncthreads();
    {
        float bb = eA;
        if (wv>0) bb += wt2[0][0];
        if (wv>1) bb += wt2[0][1];
        if (wv>2) bb += wt2[0][2];
        #pragma unroll
        for (int i=0;i<8;++i) Aa[i] += bb;      // Aa[i] = Pr_a[8t+i]
        bb = eB;
        if (wv>0) bb += wt2[1][0];
        if (wv>1) bb += wt2[1][1];
        if (wv>2) bb += wt2[1][2];
        #pragma unroll
        for (int i=0;i<8;++i) Bb[i] += bb;
    }
    // PrS writes: cells z=8t+30..8t+37 hold Pr[8t..8t+7]
    *((float2*)&QB[0][t+3] + 1) = make_float2(Aa[0], Aa[1]);
    QA[0][t+4] = make_float4(Aa[2], Aa[3], Aa[4], Aa[5]);
    *((float2*)&QB[0][t+4]) = make_float2(Aa[6], Aa[7]);
    *((float2*)&QB[1][t+3] + 1) = make_float2(Bb[0], Bb[1]);
    QA[1][t+4] = make_float4(Bb[2], Bb[3], Bb[4], Bb[5]);
    *((float2*)&QB[1][t+4]) = make_float2(Bb[6], Bb[7]);
    if (tid >= 248){
        int k = tid - 248;
        float4 z4 = make_float4(0.f,0.f,0.f,0.f);
        if (k < 4){ QA[0][k] = z4; QA[1][k] = z4; }
        else if (k < 7){ QB[0][k-4] = z4; QB[1][k-4] = z4; }
        else { *((float2*)&QB[0][3]) = make_float2(0.f,0.f);
               *((float2*)&QB[1][3]) = make_float2(0.f,0.f); }
    }
    __syncthreads();
    if (t >= 240) return;

    // ---- phase 3c: second blur outputs
    int x0 = 8*t;
    float4 lA0 = QA[0][t];   float4 lA1 = QB[0][t];
    float4 hA0 = QB[0][t+7]; float4 hA1 = QA[0][t+8];
    float4 lB0 = QA[1][t];   float4 lB1 = QB[1][t];
    float4 hB0 = QB[1][t+7]; float4 hB1 = QA[1][t+8];
    float sA[8], sB[8];
    sA[0]=hA0.x-lA0.x; sA[1]=hA0.y-lA0.y; sA[2]=hA0.z-lA0.z; sA[3]=hA0.w-lA0.w;
    sA[4]=hA1.x-lA1.x; sA[5]=hA1.y-lA1.y; sA[6]=hA1.z-lA1.z; sA[7]=hA1.w-lA1.w;
    sB[0]=hB0.x-lB0.x; sB[1]=hB0.y-lB0.y; sB[2]=hB0.z-lB0.z; sB[3]=hB0.w-lB0.w;
    sB[4]=hB1.x-lB1.x; sB[5]=hB1.y-lB1.y; sB[6]=hB1.z-lB1.z; sB[7]=hB1.w-lB1.w;

    auto prRead = [&](int pl, int v)->float{
        int z = v + 30;
        int c = z >> 2;
        float4 f = (c & 1) ? QB[pl][c>>1] : QA[pl][c>>1];
        int w = z & 3;
        return (w==0)?f.x:((w==1)?f.y:((w==2)?f.z:f.w));
    };
    if (x0 < 29){
        #pragma unroll
        for (int i=0;i<8;++i){
            int x = x0 + i;
            if (x < 29){
                sA[i] += prRead(0, 29-x) - prRead(0, 0);
                sB[i] += prRead(1, 29-x) - prRead(1, 0);
            }
        }
    }
    if (x0 + 7 > 1889){
        #pragma unroll
        for (int i=0;i<8;++i){
            int x = x0 + i;
            if (x > 1889){
                sA[i] += prRead(0, 1918) - prRead(0, 3807-x);
                sB[i] += prRead(1, 1918) - prRead(1, 3807-x);
            }
        }
    }
    const float inv = 1.0f/60.0f;
    __half2 hab[8];
    #pragma unroll
    for (int i=0;i<8;++i) hab[i] = __floats2half2_rn(sA[i]*inv, sB[i]*inv);
    size_t ro = (rb + (size_t)x0) * 2;
    *(uint4*)(abp + ro)     = *(uint4*)&hab[0];
    *(uint4*)(abp + ro + 8) = *(uint4*)&hab[4];
}

// ---------------------------------------------------------------- K5: vertical box-mean of packed ab + q
__global__ __launch_bounds__(256) void k_final(const __half* __restrict__ abp,
                                               const __half* __restrict__ dimp, float* __restrict__ q){
    int t = xcd_swz(blockIdx.x, 450)*256 + threadIdx.x;    // 480*8*30 threads, 450 blocks
    int c4 = t % NC4;
    int r  = t / NC4;
    int b  = r & 7;
    int y0 = (r >> 3) * BT;
    size_t base = (size_t)b*HWP + (size_t)c4*4;
    const __half* pab = abp + base*2;
    const __half* pd  = dimp + base;
    float* pq = q + base;
    float sa[4], sb[4];
    #pragma unroll
    for (int i=0;i<4;++i){ sa[i]=0.f; sb[i]=0.f; }
    auto accA = [&](int yy){
        int yr = reflH(yy);
        uint4 v = *(const uint4*)(pab + (size_t)yr*WW*2);
        const __half2* h = (const __half2*)&v;
        #pragma unroll
        for (int l=0;l<4;++l){
            float2 f = __half22float2(h[l]);
            sa[l]+=f.x; sb[l]+=f.y;
        }
    };
    auto accS = [&](int yy){
        int yr = reflH(yy);
        uint4 v = *(const uint4*)(pab + (size_t)yr*WW*2);
        const __half2* h = (const __half2*)&v;
        #pragma unroll
        for (int l=0;l<4;++l){
            float2 f = __half22float2(h[l]);
            sa[l]-=f.x; sb[l]-=f.y;
        }
    };
    const float inv = 1.0f/60.0f;
    for (int k=-29;k<=30;++k) accA(y0+k);
    auto emit = [&](int y){
        uint2 vd = *(const uint2*)(pd + (size_t)y*WW);
        const __half2* hd = (const __half2*)&vd;
        float2 f0 = __half22float2(hd[0]);
        float2 f1 = __half22float2(hd[1]);
        float4 o;
        o.x = (sa[0]*inv)*f0.x + sb[0]*inv;
        o.y = (sa[1]*inv)*f0.y + sb[1]*inv;
        o.z = (sa[2]*inv)*f1.x + sb[2]*inv;
        o.w = (sa[3]*inv)*f1.y + sb[3]*inv;
        *(float4*)(pq + (size_t)y*WW) = o;
    };
    emit(y0);
    for (int y=y0+1; y<y0+BT; ++y){
        accA(y+30);
        accS(y-30);
        emit(y);
    }
}

// ---------------------------------------------------------------- launch
extern "C" void kernel_launch(void* const* d_in, const int* in_sizes, int n_in,
                              void* d_out, int out_size, void* d_ws, size_t ws_size,
                              hipStream_t stream){
    const float* I = (const float*)d_in[0];
    float* qout = (float*)d_out;
    __half* ws = (__half*)d_ws;

    __half* p_dark = ws;                 // [0, NPXs)
    __half* p_eh   = ws + NPXs;          // [NPXs, 2N)
    __half* p_dim  = ws + 2*NPXs;        // [2N, 3N)
    __half* p_mp   = ws + 3*NPXs;        // [3N, 7N) packed 4 moments
    __half* p_ab   = ws;                 // aliases dark+eh (both dead before k_hab)

    k_dark_eh<<<NB*HH, 256, 0, stream>>>(I, p_dark, p_eh);
    k_erosv  <<<1080,  256, 0, stream>>>(p_eh, p_dim);
    k_blurv4 <<<450,   256, 0, stream>>>(p_dim, p_dark, p_mp);
    k_hab    <<<NB*HH, 256, 0, stream>>>(p_mp, p_ab);
    k_final  <<<450,   256, 0, stream>>>(p_ab, p_dim, qout);
}

// Round 8
// 243.522 us; speedup vs baseline: 2.5890x; 1.0115x over previous
//
#include <hip/hip_runtime.h>
#include <hip/hip_fp16.h>

#define HH 1080
#define WW 1920
#define NB 8
#define HWP (HH*WW)                 // 2,073,600
#define NPXs ((size_t)NB*HWP)       // 16,588,800
#define NC4 (WW/4)                  // 480 groups of 4 halves
#define NC8 (WW/8)                  // 240 groups of 8 halves

// LDS pad for K1: +1 word every 32
#define PADI(e) ((e) + ((e) >> 5))

__device__ __forceinline__ int reflH(int y){ int r = y < 0 ? -y : y; return r >= HH ? 2*HH-2-r : r; }

// Bijective XCD-chunked swizzle (handles nwg % 8 != 0; m204 form).
__device__ __forceinline__ int xcd_swz(int p, int nwg){
    int q = nwg >> 3, r = nwg & 7;
    int x = p & 7, idx = p >> 3;
    int start = (x < r) ? x*(q+1) : r*(q+1) + (x - r)*q;
    return start + idx;
}

__device__ __forceinline__ unsigned pkmin(unsigned a, unsigned b){
    unsigned r; asm("v_pk_min_f16 %0, %1, %2" : "=v"(r) : "v"(a), "v"(b)); return r;
}
#define INF2 0x7C007C00u

// ---------------------------------------------------------------- K1: dark channel + horizontal erosion
__global__ __launch_bounds__(256) void k_dark_eh(const float* __restrict__ I,
                                                 __half* __restrict__ dark, __half* __restrict__ eh){
    __shared__ float ds[2048];
    int bid = blockIdx.x;
    int y = bid % HH;
    int b = bid / HH;
    const float* row0 = I + (size_t)b*3*HWP + (size_t)y*WW;
    size_t rb = (size_t)b*HWP + (size_t)y*WW;
    int tid = threadIdx.x;
    if (tid < 240){
        int x0 = tid*8;
        float4 c00 = *(const float4*)(row0 + x0);
        float4 c01 = *(const float4*)(row0 + x0 + 4);
        float4 c10 = *(const float4*)(row0 + HWP + x0);
        float4 c11 = *(const float4*)(row0 + HWP + x0 + 4);
        float4 c20 = *(const float4*)(row0 + 2*HWP + x0);
        float4 c21 = *(const float4*)(row0 + 2*HWP + x0 + 4);
        float m[8];
        m[0]=fminf(fminf(c00.x,c10.x),c20.x); m[1]=fminf(fminf(c00.y,c10.y),c20.y);
        m[2]=fminf(fminf(c00.z,c10.z),c20.z); m[3]=fminf(fminf(c00.w,c10.w),c20.w);
        m[4]=fminf(fminf(c01.x,c11.x),c21.x); m[5]=fminf(fminf(c01.y,c11.y),c21.y);
        m[6]=fminf(fminf(c01.z,c11.z),c21.z); m[7]=fminf(fminf(c01.w,c11.w),c21.w);
        __half2 hd[4];
        #pragma unroll
        for (int l=0;l<4;++l) hd[l] = __floats2half2_rn(m[2*l], m[2*l+1]);
        *(uint4*)(dark + rb + x0) = *(uint4*)hd;
        #pragma unroll
        for (int i=0;i<8;++i) ds[PADI(x0+7+i)] = m[i];
    } else if (tid == 240){
        for (int i=0;i<7;++i) ds[PADI(i)] = 1e30f;
    } else if (tid == 241){
        for (int i=0;i<7;++i) ds[PADI(1927+i)] = 1e30f;
    }
    __syncthreads();
    if (tid >= 240) return;
    int x0 = tid*8;
    float s[22];
    #pragma unroll
    for (int i=0;i<22;++i) s[i] = ds[PADI(x0+i)];
    float t1[21], t2[19], t4[15];
    #pragma unroll
    for (int i=0;i<21;++i) t1[i] = fminf(s[i], s[i+1]);
    #pragma unroll
    for (int i=0;i<19;++i) t2[i] = fminf(t1[i], t1[i+2]);
    #pragma unroll
    for (int i=0;i<15;++i) t4[i] = fminf(t2[i], t2[i+4]);
    __half2 ho[4];
    #pragma unroll
    for (int l=0;l<4;++l){
        float o0 = fminf(t4[2*l],   t4[2*l+7]);
        float o1 = fminf(t4[2*l+1], t4[2*l+8]);
        ho[l] = __floats2half2_rn(o0, o1);
    }
    *(uint4*)(eh + rb + x0) = *(uint4*)ho;
}

// ---------------------------------------------------------------- K2: vertical erosion (window 15), uint4 width
__global__ __launch_bounds__(256) void k_erosv(const __half* __restrict__ eh, __half* __restrict__ dim){
    int t = xcd_swz(blockIdx.x, 540)*256 + threadIdx.x;   // 240*8*72 threads, 540 blocks
    int c8 = t % NC8;
    int r  = t / NC8;
    int b  = r & 7;
    int y0 = (r >> 3) * 15;
    const __half* sp = eh  + (size_t)b*HWP + (size_t)c8*8;
    __half*       dp = dim + (size_t)b*HWP + (size_t)c8*8;
    uint4 s[15];
    #pragma unroll
    for (int j=0;j<15;++j){
        int y = y0 - 7 + j;
        if ((unsigned)y < HH) s[j] = *(const uint4*)(sp + (size_t)y*WW);
        else s[j] = make_uint4(INF2,INF2,INF2,INF2);
    }
    #pragma unroll
    for (int j=13;j>=0;--j){
        s[j].x = pkmin(s[j].x, s[j+1].x); s[j].y = pkmin(s[j].y, s[j+1].y);
        s[j].z = pkmin(s[j].z, s[j+1].z); s[j].w = pkmin(s[j].w, s[j+1].w);
    }
    *(uint4*)(dp + (size_t)y0*WW) = s[0];
    uint4 P = make_uint4(INF2,INF2,INF2,INF2);
    #pragma unroll
    for (int j=1;j<15;++j){
        int y = y0 + 7 + j;
        uint4 nv;
        if ((unsigned)y < HH) nv = *(const uint4*)(sp + (size_t)y*WW);
        else nv = make_uint4(INF2,INF2,INF2,INF2);
        P.x = pkmin(P.x, nv.x); P.y = pkmin(P.y, nv.y);
        P.z = pkmin(P.z, nv.z); P.w = pkmin(P.w, nv.w);
        uint4 o;
        o.x = pkmin(s[j].x, P.x); o.y = pkmin(s[j].y, P.y);
        o.z = pkmin(s[j].z, P.z); o.w = pkmin(s[j].w, P.w);
        *(uint4*)(dp + (size_t)(y0+j)*WW) = o;
    }
}

// ---------------------------------------------------------------- K3: vertical box-mean of 4 moments -> packed plane
// Packed layout: px p -> halves [4p,4p+4) = {mI, mP, mIp, mII}
#define BT 54
__global__ __launch_bounds__(256) void k_blurv4(const __half* __restrict__ dimp, const __half* __restrict__ darkp,
                                                __half* __restrict__ mp){
    int t = xcd_swz(blockIdx.x, 300)*256 + threadIdx.x;    // 480*8*20 threads, 300 blocks
    int c4 = t % NC4;
    int r  = t / NC4;
    int b  = r & 7;
    int y0 = (r >> 3) * BT;
    size_t base = (size_t)b*HWP + (size_t)c4*4;
    const __half* pd = dimp + base;
    const __half* pk = darkp + base;
    float sI[4], sP[4], sIP[4], sII[4];
    #pragma unroll
    for (int i=0;i<4;++i){ sI[i]=0.f; sP[i]=0.f; sIP[i]=0.f; sII[i]=0.f; }
    auto accA = [&](int yy){
        int yr = reflH(yy);
        uint2 vd = *(const uint2*)(pd + (size_t)yr*WW);
        uint2 vk = *(const uint2*)(pk + (size_t)yr*WW);
        const __half2* hd = (const __half2*)&vd;
        const __half2* hk = (const __half2*)&vk;
        #pragma unroll
        for (int l=0;l<2;++l){
            float2 fd = __half22float2(hd[l]);
            float2 fk = __half22float2(hk[l]);
            sI[2*l]+=fd.x; sI[2*l+1]+=fd.y;
            sP[2*l]+=fk.x; sP[2*l+1]+=fk.y;
            sIP[2*l]+=fd.x*fk.x; sIP[2*l+1]+=fd.y*fk.y;
            sII[2*l]+=fd.x*fd.x; sII[2*l+1]+=fd.y*fd.y;
        }
    };
    auto accS = [&](int yy){
        int yr = reflH(yy);
        uint2 vd = *(const uint2*)(pd + (size_t)yr*WW);
        uint2 vk = *(const uint2*)(pk + (size_t)yr*WW);
        const __half2* hd = (const __half2*)&vd;
        const __half2* hk = (const __half2*)&vk;
        #pragma unroll
        for (int l=0;l<2;++l){
            float2 fd = __half22float2(hd[l]);
            float2 fk = __half22float2(hk[l]);
            sI[2*l]-=fd.x; sI[2*l+1]-=fd.y;
            sP[2*l]-=fk.x; sP[2*l+1]-=fk.y;
            sIP[2*l]-=fd.x*fk.x; sIP[2*l+1]-=fd.y*fk.y;
            sII[2*l]-=fd.x*fd.x; sII[2*l+1]-=fd.y*fd.y;
        }
    };
    const float inv = 1.0f/60.0f;
    for (int k=-29;k<=30;++k) accA(y0+k);
    auto emit = [&](int y){
        size_t off = (base + (size_t)y*WW) * 4;   // half units in packed plane
        __half2 h[4];
        h[0]=__floats2half2_rn(sI[0]*inv,  sP[0]*inv);
        h[1]=__floats2half2_rn(sIP[0]*inv, sII[0]*inv);
        h[2]=__floats2half2_rn(sI[1]*inv,  sP[1]*inv);
        h[3]=__floats2half2_rn(sIP[1]*inv, sII[1]*inv);
        *(uint4*)(mp+off) = *(uint4*)h;
        h[0]=__floats2half2_rn(sI[2]*inv,  sP[2]*inv);
        h[1]=__floats2half2_rn(sIP[2]*inv, sII[2]*inv);
        h[2]=__floats2half2_rn(sI[3]*inv,  sP[3]*inv);
        h[3]=__floats2half2_rn(sIP[3]*inv, sII[3]*inv);
        *(uint4*)(mp+off+8) = *(uint4*)h;
    };
    emit(y0);
    for (int y=y0+1; y<y0+BT; ++y){
        accA(y+30);
        accS(y-30);
        emit(y);
    }
}

// ---------------------------------------------------------------- K4: H-blur(moments) + a,b + H-blur(a,b) via prefix scans
__global__ __launch_bounds__(256) void k_hab(const __half* __restrict__ mp, __half* __restrict__ abp){
    __shared__ float4 PA[4][256];
    __shared__ float4 PB[4][256];
    __shared__ float4 QA[2][264];
    __shared__ float4 QB[2][264];
    __shared__ float wt[4][4];
    __shared__ float wt2[2][4];

    int bid = blockIdx.x;
    int y = bid % HH;
    int b = bid / HH;
    size_t rb = (size_t)b*HWP + (size_t)y*WW;
    int tid = threadIdx.x;
    int lane = tid & 63;
    int wv = tid >> 6;

    const __half* mrow = mp + rb*4;

    // ---- scan-input loads
    float xv[4][8];
    int u = tid;
    if (u >= 4 && u <= 243){
        int x0 = 8*(u-4);
        const __half* pbase = mrow + (size_t)4*x0;
        uint4 vv[4];
        vv[0] = *(const uint4*)(pbase);
        vv[1] = *(const uint4*)(pbase + 8);
        vv[2] = *(const uint4*)(pbase + 16);
        vv[3] = *(const uint4*)(pbase + 24);
        #pragma unroll
        for (int i=0;i<8;++i){
            const __half2* hh = (const __half2*)&vv[i>>1];
            float2 fa = __half22float2(hh[(i&1)*2]);
            float2 fb = __half22float2(hh[(i&1)*2+1]);
            xv[0][i]=fa.x; xv[1][i]=fa.y; xv[2][i]=fb.x; xv[3][i]=fb.y;
        }
    } else {
        #pragma unroll
        for (int i=0;i<8;++i){
            int s = 8*u + i;
            if (s >= 3 && s <= 1981){
                int j = s - 3;
                int x = j - 29;
                if (x < 0) x = -x;
                else if (x > 1919) x = 3838 - x;
                uint2 u2 = *(const uint2*)(mrow + (size_t)4*x);
                const __half2* hh = (const __half2*)&u2;
                float2 fa = __half22float2(hh[0]);
                float2 fb = __half22float2(hh[1]);
                xv[0][i]=fa.x; xv[1][i]=fa.y; xv[2][i]=fb.x; xv[3][i]=fb.y;
            } else {
                xv[0][i]=0.f; xv[1][i]=0.f; xv[2][i]=0.f; xv[3][i]=0.f;
            }
        }
    }

    // ---- local prefix + wave scan
    float ebase[4];
    #pragma unroll
    for (int p=0;p<4;++p){
        #pragma unroll
        for (int i=1;i<8;++i) xv[p][i] += xv[p][i-1];
        float v = xv[p][7];
        #pragma unroll
        for (int d=1; d<64; d<<=1){
            float tmp = __shfl_up(v, d);
            if (lane >= d) v += tmp;
        }
        ebase[p] = v - xv[p][7];
        if (lane == 63) wt[p][wv] = v;
    }
    __syncthreads();
    #pragma unroll
    for (int p=0;p<4;++p){
        float bb = ebase[p];
        if (wv > 0) bb += wt[p][0];
        if (wv > 1) bb += wt[p][1];
        if (wv > 2) bb += wt[p][2];
        #pragma unroll
        for (int i=0;i<8;++i) xv[p][i] += bb;   // xv[p][i] = Pi[8u+i]
        if (u > 0) *((float2*)&PB[p][u-1] + 1) = make_float2(xv[p][0], xv[p][1]);
        PA[p][u] = make_float4(xv[p][2], xv[p][3], xv[p][4], xv[p][5]);
        *((float2*)&PB[p][u]) = make_float2(xv[p][6], xv[p][7]);
    }
    __syncthreads();

    // ---- phase 3a: window means + a,b
    float Aa[8], Bb[8];
    int t = tid;
    if (t < 240){
        const float inv = 1.0f/60.0f;
        float mm[4][8];
        #pragma unroll
        for (int p=0;p<4;++p){
            float4 loa = PA[p][t];
            float4 lob = PB[p][t];
            float4 hib = PB[p][t+7];
            float4 hia = PA[p][t+8];
            mm[p][0]=(hib.x-loa.x)*inv; mm[p][1]=(hib.y-loa.y)*inv;
            mm[p][2]=(hib.z-loa.z)*inv; mm[p][3]=(hib.w-loa.w)*inv;
            mm[p][4]=(hia.x-lob.x)*inv; mm[p][5]=(hia.y-lob.y)*inv;
            mm[p][6]=(hia.z-lob.z)*inv; mm[p][7]=(hia.w-lob.w)*inv;
        }
        #pragma unroll
        for (int i=0;i<8;++i){
            float mI=mm[0][i], mP=mm[1][i], mIp=mm[2][i], mII=mm[3][i];
            float cov = mIp - mI*mP;
            float var = mII - mI*mI;
            float a = cov / (var + 1e-4f);
            Aa[i] = a;
            Bb[i] = mP - a*mI;
        }
    } else {
        #pragma unroll
        for (int i=0;i<8;++i){ Aa[i]=0.f; Bb[i]=0.f; }
    }

    // ---- scan2 over a and b (x-grid, 1920 values in threads 0..239)
    float eA, eB;
    {
        #pragma unroll
        for (int i=1;i<8;++i) Aa[i] += Aa[i-1];
        float v = Aa[7];
        #pragma unroll
        for (int d=1; d<64; d<<=1){
            float tmp = __shfl_up(v, d);
            if (lane >= d) v += tmp;
        }
        eA = v - Aa[7];
        if (lane==63) wt2[0][wv] = v;
    }
    {
        #pragma unroll
        for (int i=1;i<8;++i) Bb[i] += Bb[i-1];
        float v = Bb[7];
        #pragma unroll
        for (int d=1; d<64; d<<=1){
            float tmp = __shfl_up(v, d);
            if (lane >= d) v += tmp;
        }
        eB = v - Bb[7];
        if (lane==63) wt2[1][wv] = v;
    }
    __syncthreads();
    {
        float bb = eA;
        if (wv>0) bb += wt2[0][0];
        if (wv>1) bb += wt2[0][1];
        if (wv>2) bb += wt2[0][2];
        #pragma unroll
        for (int i=0;i<8;++i) Aa[i] += bb;      // Aa[i] = Pr_a[8t+i]
        bb = eB;
        if (wv>0) bb += wt2[1][0];
        if (wv>1) bb += wt2[1][1];
        if (wv>2) bb += wt2[1][2];
        #pragma unroll
        for (int i=0;i<8;++i) Bb[i] += bb;
    }
    // PrS writes: cells z=8t+30..8t+37 hold Pr[8t..8t+7]
    *((float2*)&QB[0][t+3] + 1) = make_float2(Aa[0], Aa[1]);
    QA[0][t+4] = make_float4(Aa[2], Aa[3], Aa[4], Aa[5]);
    *((float2*)&QB[0][t+4]) = make_float2(Aa[6], Aa[7]);
    *((float2*)&QB[1][t+3] + 1) = make_float2(Bb[0], Bb[1]);
    QA[1][t+4] = make_float4(Bb[2], Bb[3], Bb[4], Bb[5]);
    *((float2*)&QB[1][t+4]) = make_float2(Bb[6], Bb[7]);
    if (tid >= 248){
        int k = tid - 248;
        float4 z4 = make_float4(0.f,0.f,0.f,0.f);
        if (k < 4){ QA[0][k] = z4; QA[1][k] = z4; }
        else if (k < 7){ QB[0][k-4] = z4; QB[1][k-4] = z4; }
        else { *((float2*)&QB[0][3]) = make_float2(0.f,0.f);
               *((float2*)&QB[1][3]) = make_float2(0.f,0.f); }
    }
    __syncthreads();
    if (t >= 240) return;

    // ---- phase 3c: second blur outputs
    int x0 = 8*t;
    float4 lA0 = QA[0][t];   float4 lA1 = QB[0][t];
    float4 hA0 = QB[0][t+7]; float4 hA1 = QA[0][t+8];
    float4 lB0 = QA[1][t];   float4 lB1 = QB[1][t];
    float4 hB0 = QB[1][t+7]; float4 hB1 = QA[1][t+8];
    float sA[8], sB[8];
    sA[0]=hA0.x-lA0.x; sA[1]=hA0.y-lA0.y; sA[2]=hA0.z-lA0.z; sA[3]=hA0.w-lA0.w;
    sA[4]=hA1.x-lA1.x; sA[5]=hA1.y-lA1.y; sA[6]=hA1.z-lA1.z; sA[7]=hA1.w-lA1.w;
    sB[0]=hB0.x-lB0.x; sB[1]=hB0.y-lB0.y; sB[2]=hB0.z-lB0.z; sB[3]=hB0.w-lB0.w;
    sB[4]=hB1.x-lB1.x; sB[5]=hB1.y-lB1.y; sB[6]=hB1.z-lB1.z; sB[7]=hB1.w-lB1.w;

    auto prRead = [&](int pl, int v)->float{
        int z = v + 30;
        int c = z >> 2;
        float4 f = (c & 1) ? QB[pl][c>>1] : QA[pl][c>>1];
        int w = z & 3;
        return (w==0)?f.x:((w==1)?f.y:((w==2)?f.z:f.w));
    };
    if (x0 < 29){
        #pragma unroll
        for (int i=0;i<8;++i){
            int x = x0 + i;
            if (x < 29){
                sA[i] += prRead(0, 29-x) - prRead(0, 0);
                sB[i] += prRead(1, 29-x) - prRead(1, 0);
            }
        }
    }
    if (x0 + 7 > 1889){
        #pragma unroll
        for (int i=0;i<8;++i){
            int x = x0 + i;
            if (x > 1889){
                sA[i] += prRead(0, 1918) - prRead(0, 3807-x);
                sB[i] += prRead(1, 1918) - prRead(1, 3807-x);
            }
        }
    }
    const float inv = 1.0f/60.0f;
    __half2 hab[8];
    #pragma unroll
    for (int i=0;i<8;++i) hab[i] = __floats2half2_rn(sA[i]*inv, sB[i]*inv);
    size_t ro = (rb + (size_t)x0) * 2;
    *(uint4*)(abp + ro)     = *(uint4*)&hab[0];
    *(uint4*)(abp + ro + 8) = *(uint4*)&hab[4];
}

// ---------------------------------------------------------------- K5: vertical box-mean of packed ab + q
__global__ __launch_bounds__(256) void k_final(const __half* __restrict__ abp,
                                               const __half* __restrict__ dimp, float* __restrict__ q){
    int t = xcd_swz(blockIdx.x, 300)*256 + threadIdx.x;    // 480*8*20 threads, 300 blocks
    int c4 = t % NC4;
    int r  = t / NC4;
    int b  = r & 7;
    int y0 = (r >> 3) * BT;
    size_t base = (size_t)b*HWP + (size_t)c4*4;
    const __half* pab = abp + base*2;
    const __half* pd  = dimp + base;
    float* pq = q + base;
    float sa[4], sb[4];
    #pragma unroll
    for (int i=0;i<4;++i){ sa[i]=0.f; sb[i]=0.f; }
    auto accA = [&](int yy){
        int yr = reflH(yy);
        uint4 v = *(const uint4*)(pab + (size_t)yr*WW*2);
        const __half2* h = (const __half2*)&v;
        #pragma unroll
        for (int l=0;l<4;++l){
            float2 f = __half22float2(h[l]);
            sa[l]+=f.x; sb[l]+=f.y;
        }
    };
    auto accS = [&](int yy){
        int yr = reflH(yy);
        uint4 v = *(const uint4*)(pab + (size_t)yr*WW*2);
        const __half2* h = (const __half2*)&v;
        #pragma unroll
        for (int l=0;l<4;++l){
            float2 f = __half22float2(h[l]);
            sa[l]-=f.x; sb[l]-=f.y;
        }
    };
    const float inv = 1.0f/60.0f;
    for (int k=-29;k<=30;++k) accA(y0+k);
    auto emit = [&](int y){
        uint2 vd = *(const uint2*)(pd + (size_t)y*WW);
        const __half2* hd = (const __half2*)&vd;
        float2 f0 = __half22float2(hd[0]);
        float2 f1 = __half22float2(hd[1]);
        float4 o;
        o.x = (sa[0]*inv)*f0.x + sb[0]*inv;
        o.y = (sa[1]*inv)*f0.y + sb[1]*inv;
        o.z = (sa[2]*inv)*f1.x + sb[2]*inv;
        o.w = (sa[3]*inv)*f1.y + sb[3]*inv;
        *(float4*)(pq + (size_t)y*WW) = o;
    };
    emit(y0);
    for (int y=y0+1; y<y0+BT; ++y){
        accA(y+30);
        accS(y-30);
        emit(y);
    }
}

// ---------------------------------------------------------------- launch
extern "C" void kernel_launch(void* const* d_in, const int* in_sizes, int n_in,
                              void* d_out, int out_size, void* d_ws, size_t ws_size,
                              hipStream_t stream){
    const float* I = (const float*)d_in[0];
    float* qout = (float*)d_out;
    __half* ws = (__half*)d_ws;

    __half* p_dark = ws;                 // [0, NPXs)
    __half* p_eh   = ws + NPXs;          // [NPXs, 2N)
    __half* p_dim  = ws + 2*NPXs;        // [2N, 3N)
    __half* p_mp   = ws + 3*NPXs;        // [3N, 7N) packed 4 moments
    __half* p_ab   = ws;                 // aliases dark+eh (both dead before k_hab)

    k_dark_eh<<<NB*HH, 256, 0, stream>>>(I, p_dark, p_eh);
    k_erosv  <<<540,   256, 0, stream>>>(p_eh, p_dim);
    k_blurv4 <<<300,   256, 0, stream>>>(p_dim, p_dark, p_mp);
    k_hab    <<<NB*HH, 256, 0, stream>>>(p_mp, p_ab);
    k_final  <<<300,   256, 0, stream>>>(p_ab, p_dim, qout);
}